// Round 1
// baseline (301.010 us; speedup 1.0000x reference)
//
#include <hip/hip_runtime.h>

// AutoregBlock: B=1024, DIM=384, HID=64, K=8, G=48, MID=128
// One 1024-thread block (16 waves) per batch element, TWO blocks/CU:
// LDS cut 147KB -> ~75KB (c-halved M, 96-row FFN passes, weights direct
// from global bf16), VGPR capped at 64 via __launch_bounds__(1024,8).
// Region sRB (24KB) timeline: sM half (P2/P3) -> sPg (P3e..P4) -> sZ1 (P6).

#define EPSF 1e-6f

typedef __attribute__((ext_vector_type(8))) short bf16x8;
typedef __attribute__((ext_vector_type(4))) float f32x4;
typedef __attribute__((ext_vector_type(4))) unsigned short u16x4;

__device__ __forceinline__ unsigned short f2bf(float f) {
    union { float f; unsigned int u; } v; v.f = f;
    unsigned int r = v.u + 0x7fffu + ((v.u >> 16) & 1u);
    return (unsigned short)(r >> 16);
}
__device__ __forceinline__ float bf2f(unsigned short h) {
    union { unsigned int u; float f; } v; v.u = ((unsigned int)h) << 16;
    return v.f;
}
// leaky(v) = max(v, 0.01v): 2 VALU ops, no divergence
__device__ __forceinline__ float leaky(float v) { return fmaxf(v, 0.01f * v); }
__device__ __forceinline__ int key8(int r) { return (r ^ (r >> 3)) & 7; }
// gelu tanh-form, 8 instr: t = u*(A + B*u^2); e = expf(t); g = u - u*rcp(e+1)
__device__ __forceinline__ float gelu_f(float u) {
    float t = u * (1.5957691216f + 0.0713548163f * (u * u));
    float e = __expf(t);
    float r = __builtin_amdgcn_rcpf(e + 1.0f);
    return fmaf(-u, r, u);
}

// ws: [0,18432) floats projT (48x384); then bf16: dwB (128x64), uwB (64x128)
__global__ void prep(const float* __restrict__ proj_w,
                     const float* __restrict__ down_w,
                     const float* __restrict__ up_w,
                     float* __restrict__ ws) {
    int idx = blockIdx.x * blockDim.x + threadIdx.x;
    unsigned short* wb = (unsigned short*)(ws + 18432);
    if (idx < 18432) {
        int i = idx / 48, g = idx % 48;
        ws[g * 384 + i] = proj_w[idx];
    } else if (idx < 26624) {
        int k = idx - 18432;
        wb[k] = f2bf(down_w[k]);
    } else if (idx < 34816) {
        int k = idx - 26624;
        wb[8192 + k] = f2bf(up_w[k]);
    }
}

__global__ __launch_bounds__(1024, 8) void fused_main(
    const float* __restrict__ x,
    const float* __restrict__ W,
    const float* __restrict__ bb,
    const float* __restrict__ patch_weight,
    const float* __restrict__ pw1, const float* __restrict__ pb1,
    const float* __restrict__ pw2, const float* __restrict__ pb2,
    const float* __restrict__ proj_b,
    const float* __restrict__ down_b,
    const float* __restrict__ up_b,
    const float* __restrict__ ws,
    float* __restrict__ out)
{
    __shared__ __align__(16) unsigned short sH[24576];   // 48 KB H bf16 [i][c] swizzled
    __shared__ __align__(16) unsigned short sRB[12288];  // 24 KB region: sM half -> sPg -> sZ1
    __shared__ float sw[64];
    __shared__ float srw[48];
    __shared__ float sScale[384];
    __shared__ float sDb[128];
    __shared__ float sUb[64];

    const int t = threadIdx.x;
    const int b = blockIdx.x;
    const int wv = t >> 6, lane = t & 63, q = lane >> 4, r = lane & 15;
    const float* projT = ws;
    const unsigned short* dwB = (const unsigned short*)(ws + 18432);
    const unsigned short* uwB = dwB + 8192;
    unsigned short* sM  = sRB;            // 48x256 bf16 (one c-half at a time)
    float* sPg = (float*)sRB;             // 48x49 fp32 (9408 B)
    unsigned short* sZ1 = sRB;            // 96x128 bf16 (24576 B)

    // ---- P0: softmax of the 64 patch weights (wave 0) ----
    if (t < 64) {
        float p = patch_weight[t];
        float m = p;
        for (int o = 32; o > 0; o >>= 1) m = fmaxf(m, __shfl_xor(m, o));
        float e = __expf(p - m);
        float s = e;
        for (int o = 32; o > 0; o >>= 1) s += __shfl_xor(s, o);
        sw[t] = e * __builtin_amdgcn_rcpf(s);
    }

    // ---- P1: H = gelu(x*W + inv*b) -> sH bf16 (swizzled) ----
    for (int j = 0; j < 6; ++j) {
        int idx4 = j * 1024 + t;
        int base = idx4 * 4;
        int i = base >> 6, c0 = base & 63;
        float4 w4 = ((const float4*)W)[idx4];
        float4 b4 = ((const float4*)bb)[idx4];
        float xi  = x[b * 384 + i];
        float inv = __builtin_amdgcn_rcpf(fabsf(xi) + EPSF);
        u16x4 hv;
        hv[0] = f2bf(gelu_f(fmaf(xi, w4.x, inv * b4.x)));
        hv[1] = f2bf(gelu_f(fmaf(xi, w4.y, inv * b4.y)));
        hv[2] = f2bf(gelu_f(fmaf(xi, w4.z, inv * b4.z)));
        hv[3] = f2bf(gelu_f(fmaf(xi, w4.w, inv * b4.w)));
        int cb = c0 >> 3, cc = c0 & 7;
        *(u16x4*)&sH[i * 64 + ((cb ^ key8(i)) << 3) + cc] = hv;
    }
    __syncthreads();

    // ---- P2/P3 in two c-halves: M_h[g, l*32+c'] = sum_k w[k,l]*H[8g+k, 32h+c']
    //      then Pg += M_h @ H_h^T (MFMA, K=256 per half) ----
    f32x4 pacc = {0.f, 0.f, 0.f, 0.f};
    for (int hc = 0; hc < 2; ++hc) {
        if (t < 768) {
            const int cb = t & 3, lp = (t >> 2) & 3, g = t >> 4;
            float acc[2][8];
            #pragma unroll
            for (int dl = 0; dl < 2; ++dl)
                #pragma unroll
                for (int cc = 0; cc < 8; ++cc) acc[dl][cc] = 0.0f;
            #pragma unroll
            for (int k = 0; k < 8; ++k) {
                int i = g * 8 + k;
                int cbh = hc * 4 + cb;
                bf16x8 hv = *(const bf16x8*)&sH[i * 64 + ((cbh ^ key8(i)) << 3)];
                float w0 = sw[k * 8 + lp * 2];
                float w1 = sw[k * 8 + lp * 2 + 1];
                float hf[8];
                #pragma unroll
                for (int cc = 0; cc < 8; ++cc) hf[cc] = bf2f((unsigned short)hv[cc]);
                #pragma unroll
                for (int cc = 0; cc < 8; ++cc) {
                    acc[0][cc] = fmaf(w0, hf[cc], acc[0][cc]);
                    acc[1][cc] = fmaf(w1, hf[cc], acc[1][cc]);
                }
            }
            #pragma unroll
            for (int dl = 0; dl < 2; ++dl) {
                int l = lp * 2 + dl;
                int cbl = l * 4 + cb;                       // 0..31 block within 256-row
                int cbs = (cbl & 24) | ((cbl ^ key8(g)) & 7);
                bf16x8 mv;
                #pragma unroll
                for (int cc = 0; cc < 8; ++cc) mv[cc] = (short)f2bf(acc[dl][cc]);
                *(bf16x8*)&sM[g * 256 + (cbs << 3)] = mv;
            }
        }
        __syncthreads();
        if (wv < 9) {
            const int tg = wv / 3, th = wv % 3;
            #pragma unroll
            for (int ks = 0; ks < 8; ++ks) {                // l == ks, c' = q*8..+7
                int g = tg * 16 + r;
                int cbl = ks * 4 + q;
                int cbs = (cbl & 24) | ((cbl ^ key8(g)) & 7);
                bf16x8 av = *(const bf16x8*)&sM[g * 256 + (cbs << 3)];
                int i = (th * 16 + r) * 8 + ks;
                int cbh = hc * 4 + q;
                bf16x8 bv = *(const bf16x8*)&sH[i * 64 + ((cbh ^ key8(i)) << 3)];
                pacc = __builtin_amdgcn_mfma_f32_16x16x32_bf16(av, bv, pacc, 0, 0, 0);
            }
        }
        __syncthreads();   // protects sM overwrite (hc=0) / region handoff (hc=1)
    }

    // ---- pair transforms + sPg write; bias loads ----
    if (wv < 9) {
        const int tg = wv / 3, th = wv % 3;
        #pragma unroll
        for (int reg = 0; reg < 4; ++reg) {
            int g = tg * 16 + q * 4 + reg;
            int h = th * 16 + r;
            int idx = g * 48 + h;
            float v = pacc[reg];
            v = leaky(fmaf(v, pw1[idx], pb1[idx]));
            v = leaky(fmaf(v, pw2[idx], pb2[idx]));
            sPg[g * 49 + h] = v;
        }
    }
    if (t < 128) sDb[t] = down_b[t];
    else if (t < 192) sUb[t - 128] = up_b[t - 128];
    __syncthreads();

    // ---- P4: row softmax -> row_weights; 4 rows/wave, 16 lanes x 3 elems ----
    if (wv < 12) {
        int row = wv * 4 + (lane >> 4);
        int idx = lane & 15;
        const float* pr = &sPg[row * 49 + idx * 3];
        float v0 = pr[0], v1 = pr[1], v2 = pr[2];
        float m = fmaxf(v0, fmaxf(v1, v2));
        #pragma unroll
        for (int o = 8; o > 0; o >>= 1) m = fmaxf(m, __shfl_xor(m, o));
        float e0 = __expf(v0 - m), e1 = __expf(v1 - m), e2 = __expf(v2 - m);
        float s = e0 + e1 + e2;
        #pragma unroll
        for (int o = 8; o > 0; o >>= 1) s += __shfl_xor(s, o);
        float rs = __builtin_amdgcn_rcpf(s);
        float p0 = e0 * rs, p1 = e1 * rs, p2 = e2 * rs;
        float rw = __builtin_amdgcn_rcpf(fmaf(p0, p0, 1.0f))
                 + __builtin_amdgcn_rcpf(fmaf(p1, p1, 1.0f))
                 + __builtin_amdgcn_rcpf(fmaf(p2, p2, 1.0f));
        #pragma unroll
        for (int o = 8; o > 0; o >>= 1) rw += __shfl_xor(rw, o);
        if (idx == 0) srw[row] = rw;
    }
    __syncthreads();

    // ---- P6: FFN in four 96-row passes; P5 (scales) fused into pass 0 ----
    const int mg = wv >> 3, ng = wv & 7;
    #pragma unroll 1
    for (int rt = 0; rt < 4; ++rt) {
        const int r0 = rt * 96;
        // scales (pass 0 only): overlaps with z1 MFMA of other waves
        if (rt == 0 && t < 384) {
            float s = proj_b[t];
            #pragma unroll 4
            for (int g = 0; g < 48; ++g) s = fmaf(srw[g], projT[g * 384 + t], s);
            sScale[t] = s;
        }
        // z1 MFMA: (H @ dw^T), supertile 3m x 1n, B direct from global bf16
        f32x4 zacc[3];
        #pragma unroll
        for (int a = 0; a < 3; ++a) zacc[a] = (f32x4){0.f, 0.f, 0.f, 0.f};
        #pragma unroll
        for (int ks = 0; ks < 2; ++ks) {
            int cb = ks * 4 + q;
            int n = ng * 16 + r;
            bf16x8 bv = *(const bf16x8*)&dwB[n * 64 + cb * 8];
            #pragma unroll
            for (int a = 0; a < 3; ++a) {
                int i = r0 + (mg * 3 + a) * 16 + r;
                bf16x8 av = *(const bf16x8*)&sH[i * 64 + ((cb ^ key8(i)) << 3)];
                zacc[a] = __builtin_amdgcn_mfma_f32_16x16x32_bf16(av, bv, zacc[a], 0, 0, 0);
            }
        }
        __syncthreads();   // sScale ready (rt0); prior pass z2 reads of sZ1 done
        // z1 epilogue -> sZ1 bf16 swizzled
        #pragma unroll
        for (int a = 0; a < 3; ++a) {
            #pragma unroll
            for (int reg = 0; reg < 4; ++reg) {
                int rl = (mg * 3 + a) * 16 + q * 4 + reg;
                int m = ng * 16 + r;
                float v = leaky(fmaf(zacc[a][reg], sScale[r0 + rl], sDb[m]));
                int cb2 = m >> 3;
                int cbs2 = (cb2 & 8) | ((cb2 ^ key8(rl)) & 7);
                sZ1[rl * 128 + (cbs2 << 3) + (m & 7)] = f2bf(v);
            }
        }
        __syncthreads();   // sZ1 visible
        // z2 = leaky(z1 @ uw^T + ub) -> out; 24 tiles, waves 0..7 take 2
        int ntl = (wv < 8) ? 2 : 1;
        for (int tt = 0; tt < ntl; ++tt) {
            int tau = wv + tt * 16;
            int mt = tau >> 2, nt = tau & 3;
            f32x4 oacc = {0.f, 0.f, 0.f, 0.f};
            #pragma unroll
            for (int ks = 0; ks < 4; ++ks) {
                int cb = ks * 4 + q;
                int p = nt * 16 + r;
                bf16x8 bv = *(const bf16x8*)&uwB[p * 128 + cb * 8];
                int rl = mt * 16 + r;
                int cbsA = (cb & 8) | ((cb ^ key8(rl)) & 7);
                bf16x8 av = *(const bf16x8*)&sZ1[rl * 128 + (cbsA << 3)];
                oacc = __builtin_amdgcn_mfma_f32_16x16x32_bf16(av, bv, oacc, 0, 0, 0);
            }
            #pragma unroll
            for (int reg = 0; reg < 4; ++reg) {
                int i = r0 + mt * 16 + q * 4 + reg;
                int cp = nt * 16 + r;
                out[(b * 384 + i) * 64 + cp] = leaky(oacc[reg] + sUb[cp]);
            }
        }
        // no trailing barrier: next pass z1-MFMA touches only sH/global;
        // its post-MFMA barrier orders sZ1 overwrite after these z2 reads.
    }
}

extern "C" void kernel_launch(void* const* d_in, const int* in_sizes, int n_in,
                              void* d_out, int out_size, void* d_ws, size_t ws_size,
                              hipStream_t stream) {
    const float* x      = (const float*)d_in[0];
    const float* W      = (const float*)d_in[1];
    const float* bb     = (const float*)d_in[2];
    const float* pw     = (const float*)d_in[3];
    const float* pw1    = (const float*)d_in[4];
    const float* pb1    = (const float*)d_in[5];
    const float* pw2    = (const float*)d_in[6];
    const float* pb2    = (const float*)d_in[7];
    const float* proj_w = (const float*)d_in[8];
    const float* proj_b = (const float*)d_in[9];
    const float* down_w = (const float*)d_in[10];
    const float* down_b = (const float*)d_in[11];
    const float* up_w   = (const float*)d_in[12];
    const float* up_b   = (const float*)d_in[13];
    float* out = (float*)d_out;
    float* ws  = (float*)d_ws;

    prep<<<(34816 + 255) / 256, 256, 0, stream>>>(proj_w, down_w, up_w, ws);
    fused_main<<<1024, 1024, 0, stream>>>(x, W, bb, pw, pw1, pb1, pw2, pb2,
                                          proj_b, down_b, up_b, ws, out);
}

// Round 3
// 188.157 us; speedup vs baseline: 1.5998x; 1.5998x over previous
//
#include <hip/hip_runtime.h>

// AutoregBlock: B=1024, DIM=384, HID=64, K=8, G=48, MID=128
// One 512-thread block (8 waves) per batch element, TWO independent blocks/CU
// (LDS ~75KB, VGPR budget 128 via __launch_bounds__(512,4) -> no spills).
// Region sRB (24KB) timeline: sM half (P2/P3) -> sPg (P3e..P4) -> sZ1 (P6).
// R2 bug fixed: sUb was never loaded (dead else-if under 128-thread guard).

#define EPSF 1e-6f

typedef __attribute__((ext_vector_type(8))) short bf16x8;
typedef __attribute__((ext_vector_type(4))) float f32x4;
typedef __attribute__((ext_vector_type(4))) unsigned short u16x4;

__device__ __forceinline__ unsigned short f2bf(float f) {
    union { float f; unsigned int u; } v; v.f = f;
    unsigned int r = v.u + 0x7fffu + ((v.u >> 16) & 1u);
    return (unsigned short)(r >> 16);
}
__device__ __forceinline__ float bf2f(unsigned short h) {
    union { unsigned int u; float f; } v; v.u = ((unsigned int)h) << 16;
    return v.f;
}
// leaky(v) = max(v, 0.01v): 2 VALU ops, no divergence
__device__ __forceinline__ float leaky(float v) { return fmaxf(v, 0.01f * v); }
__device__ __forceinline__ int key8(int r) { return (r ^ (r >> 3)) & 7; }
// gelu tanh-form: t = u*(A + B*u^2); e = expf(t); g = u - u*rcp(e+1)
__device__ __forceinline__ float gelu_f(float u) {
    float t = u * (1.5957691216f + 0.0713548163f * (u * u));
    float e = __expf(t);
    float r = __builtin_amdgcn_rcpf(e + 1.0f);
    return fmaf(-u, r, u);
}

// ws: [0,18432) floats projT (48x384); then bf16: dwB (128x64), uwB (64x128)
__global__ void prep(const float* __restrict__ proj_w,
                     const float* __restrict__ down_w,
                     const float* __restrict__ up_w,
                     float* __restrict__ ws) {
    int idx = blockIdx.x * blockDim.x + threadIdx.x;
    unsigned short* wb = (unsigned short*)(ws + 18432);
    if (idx < 18432) {
        int i = idx / 48, g = idx % 48;
        ws[g * 384 + i] = proj_w[idx];
    } else if (idx < 26624) {
        int k = idx - 18432;
        wb[k] = f2bf(down_w[k]);
    } else if (idx < 34816) {
        int k = idx - 26624;
        wb[8192 + k] = f2bf(up_w[k]);
    }
}

__global__ __launch_bounds__(512, 4) void fused_main(
    const float* __restrict__ x,
    const float* __restrict__ W,
    const float* __restrict__ bb,
    const float* __restrict__ patch_weight,
    const float* __restrict__ pw1, const float* __restrict__ pb1,
    const float* __restrict__ pw2, const float* __restrict__ pb2,
    const float* __restrict__ proj_b,
    const float* __restrict__ down_b,
    const float* __restrict__ up_b,
    const float* __restrict__ ws,
    float* __restrict__ out)
{
    __shared__ __align__(16) unsigned short sH[24576];   // 48 KB H bf16 [i][c] swizzled
    __shared__ __align__(16) unsigned short sRB[12288];  // 24 KB region: sM half -> sPg -> sZ1
    __shared__ float sw[64];
    __shared__ float srw[48];
    __shared__ float sScale[384];
    __shared__ float sDb[128];
    __shared__ float sUb[64];

    const int t = threadIdx.x;
    const int b = blockIdx.x;
    const int wv = t >> 6, lane = t & 63, q = lane >> 4, r = lane & 15;
    const float* projT = ws;
    const unsigned short* dwB = (const unsigned short*)(ws + 18432);
    const unsigned short* uwB = dwB + 8192;
    unsigned short* sM  = sRB;            // 48x256 bf16 (one c-half at a time)
    float* sPg = (float*)sRB;             // 48x49 fp32 (9408 B)
    unsigned short* sZ1 = sRB;            // 96x128 bf16 (24576 B)

    // ---- P0: softmax of the 64 patch weights (wave 0) ----
    if (t < 64) {
        float p = patch_weight[t];
        float m = p;
        for (int o = 32; o > 0; o >>= 1) m = fmaxf(m, __shfl_xor(m, o));
        float e = __expf(p - m);
        float s = e;
        for (int o = 32; o > 0; o >>= 1) s += __shfl_xor(s, o);
        sw[t] = e * __builtin_amdgcn_rcpf(s);
    }

    // ---- P1: H = gelu(x*W + inv*b) -> sH bf16 (swizzled) ----
    for (int j = 0; j < 12; ++j) {
        int idx4 = j * 512 + t;
        int base = idx4 * 4;
        int i = base >> 6, c0 = base & 63;
        float4 w4 = ((const float4*)W)[idx4];
        float4 b4 = ((const float4*)bb)[idx4];
        float xi  = x[b * 384 + i];
        float inv = __builtin_amdgcn_rcpf(fabsf(xi) + EPSF);
        u16x4 hv;
        hv[0] = f2bf(gelu_f(fmaf(xi, w4.x, inv * b4.x)));
        hv[1] = f2bf(gelu_f(fmaf(xi, w4.y, inv * b4.y)));
        hv[2] = f2bf(gelu_f(fmaf(xi, w4.z, inv * b4.z)));
        hv[3] = f2bf(gelu_f(fmaf(xi, w4.w, inv * b4.w)));
        int cb = c0 >> 3, cc = c0 & 7;
        *(u16x4*)&sH[i * 64 + ((cb ^ key8(i)) << 3) + cc] = hv;
    }
    __syncthreads();

    // ---- P2/P3 in two c-halves: M_h[g, l*32+c'] = sum_k w[k,l]*H[8g+k, 32h+c']
    //      then Pg += M_h @ H_h^T (MFMA, K=256 per half) ----
    f32x4 pacc  = {0.f, 0.f, 0.f, 0.f};
    f32x4 pacc8 = {0.f, 0.f, 0.f, 0.f};
    for (int hc = 0; hc < 2; ++hc) {
        if (t < 384) {
            // t = g*8 + lq*4 + cb ; 48 g x 2 lq x 4 cb
            const int cb = t & 3, lq = (t >> 2) & 1, g = t >> 3;
            float acc[4][8];
            #pragma unroll
            for (int a = 0; a < 4; ++a)
                #pragma unroll
                for (int cc = 0; cc < 8; ++cc) acc[a][cc] = 0.0f;
            #pragma unroll
            for (int k = 0; k < 8; ++k) {
                int i = g * 8 + k;
                int cbh = hc * 4 + cb;
                bf16x8 hv = *(const bf16x8*)&sH[i * 64 + ((cbh ^ key8(i)) << 3)];
                f32x4 w4 = *(const f32x4*)&sw[k * 8 + lq * 4];
                float hf[8];
                #pragma unroll
                for (int cc = 0; cc < 8; ++cc) hf[cc] = bf2f((unsigned short)hv[cc]);
                #pragma unroll
                for (int a = 0; a < 4; ++a)
                    #pragma unroll
                    for (int cc = 0; cc < 8; ++cc)
                        acc[a][cc] = fmaf(w4[a], hf[cc], acc[a][cc]);
            }
            #pragma unroll
            for (int a = 0; a < 4; ++a) {
                int l = lq * 4 + a;
                int cbl = l * 4 + cb;                       // 0..31 block within 256
                int cbs = (cbl & 24) | ((cbl ^ key8(g)) & 7);
                bf16x8 mv;
                #pragma unroll
                for (int cc = 0; cc < 8; ++cc) mv[cc] = (short)f2bf(acc[a][cc]);
                *(bf16x8*)&sM[g * 256 + (cbs << 3)] = mv;
            }
        } else if (hc == 0) {
            // waves 6..7 (threads 384..511): biases (overlaps P2 compute)
            int tt = t - 384;                 // 0..127
            if (tt < 128) sDb[tt] = down_b[tt];
            if (tt < 64)  sUb[tt] = up_b[tt];
        }
        __syncthreads();
        // P3: 9 tiles of 16x16 over 8 waves (wave 7 takes tiles 7 and 8)
        {
            const int tg = wv / 3, th = wv % 3;
            #pragma unroll
            for (int ks = 0; ks < 8; ++ks) {                // l == ks, c' = q*8..+7
                int g = tg * 16 + r;
                int cbl = ks * 4 + q;
                int cbs = (cbl & 24) | ((cbl ^ key8(g)) & 7);
                bf16x8 av = *(const bf16x8*)&sM[g * 256 + (cbs << 3)];
                int i = (th * 16 + r) * 8 + ks;
                int cbh = hc * 4 + q;
                bf16x8 bv = *(const bf16x8*)&sH[i * 64 + ((cbh ^ key8(i)) << 3)];
                pacc = __builtin_amdgcn_mfma_f32_16x16x32_bf16(av, bv, pacc, 0, 0, 0);
            }
            if (wv == 7) {                                   // tile 8: tg=2, th=2
                #pragma unroll
                for (int ks = 0; ks < 8; ++ks) {
                    int g = 32 + r;
                    int cbl = ks * 4 + q;
                    int cbs = (cbl & 24) | ((cbl ^ key8(g)) & 7);
                    bf16x8 av = *(const bf16x8*)&sM[g * 256 + (cbs << 3)];
                    int i = (32 + r) * 8 + ks;
                    int cbh = hc * 4 + q;
                    bf16x8 bv = *(const bf16x8*)&sH[i * 64 + ((cbh ^ key8(i)) << 3)];
                    pacc8 = __builtin_amdgcn_mfma_f32_16x16x32_bf16(av, bv, pacc8, 0, 0, 0);
                }
            }
        }
        __syncthreads();   // protects sM overwrite (hc=0) / region handoff (hc=1)
    }

    // ---- pair transforms + sPg write ----
    {
        const int tg = wv / 3, th = wv % 3;
        #pragma unroll
        for (int reg = 0; reg < 4; ++reg) {
            int g = tg * 16 + q * 4 + reg;
            int h = th * 16 + r;
            int idx = g * 48 + h;
            float v = pacc[reg];
            v = leaky(fmaf(v, pw1[idx], pb1[idx]));
            v = leaky(fmaf(v, pw2[idx], pb2[idx]));
            sPg[g * 49 + h] = v;
        }
        if (wv == 7) {
            #pragma unroll
            for (int reg = 0; reg < 4; ++reg) {
                int g = 32 + q * 4 + reg;
                int h = 32 + r;
                int idx = g * 48 + h;
                float v = pacc8[reg];
                v = leaky(fmaf(v, pw1[idx], pb1[idx]));
                v = leaky(fmaf(v, pw2[idx], pb2[idx]));
                sPg[g * 49 + h] = v;
            }
        }
    }
    __syncthreads();

    // ---- P4: row softmax -> row_weights; waves 0..5, 8 rows each ----
    if (wv < 6) {
        #pragma unroll
        for (int it = 0; it < 2; ++it) {
            int row = wv * 8 + it * 4 + (lane >> 4);
            int idx = lane & 15;
            const float* pr = &sPg[row * 49 + idx * 3];
            float v0 = pr[0], v1 = pr[1], v2 = pr[2];
            float m = fmaxf(v0, fmaxf(v1, v2));
            #pragma unroll
            for (int o = 8; o > 0; o >>= 1) m = fmaxf(m, __shfl_xor(m, o));
            float e0 = __expf(v0 - m), e1 = __expf(v1 - m), e2 = __expf(v2 - m);
            float s = e0 + e1 + e2;
            #pragma unroll
            for (int o = 8; o > 0; o >>= 1) s += __shfl_xor(s, o);
            float rs = __builtin_amdgcn_rcpf(s);
            float p0 = e0 * rs, p1 = e1 * rs, p2 = e2 * rs;
            float rw = __builtin_amdgcn_rcpf(fmaf(p0, p0, 1.0f))
                     + __builtin_amdgcn_rcpf(fmaf(p1, p1, 1.0f))
                     + __builtin_amdgcn_rcpf(fmaf(p2, p2, 1.0f));
            #pragma unroll
            for (int o = 8; o > 0; o >>= 1) rw += __shfl_xor(rw, o);
            if (idx == 0) srw[row] = rw;
        }
    }
    __syncthreads();

    // ---- P6: FFN in four 96-row passes; P5 (scales) fused into pass 0 ----
    #pragma unroll 1
    for (int rt = 0; rt < 4; ++rt) {
        const int r0 = rt * 96;
        // scales (pass 0 only)
        if (rt == 0 && t < 384) {
            float s = proj_b[t];
            #pragma unroll 4
            for (int g = 0; g < 48; ++g) s = fmaf(srw[g], projT[g * 384 + t], s);
            sScale[t] = s;
        }
        // z1 = H @ dw^T, supertile 6m x 1n, B direct from global bf16
        f32x4 zacc[6];
        #pragma unroll
        for (int a = 0; a < 6; ++a) zacc[a] = (f32x4){0.f, 0.f, 0.f, 0.f};
        #pragma unroll
        for (int ks = 0; ks < 2; ++ks) {
            int cb = ks * 4 + q;
            int n = wv * 16 + r;
            bf16x8 bv = *(const bf16x8*)&dwB[n * 64 + cb * 8];
            #pragma unroll
            for (int a = 0; a < 6; ++a) {
                int i = r0 + a * 16 + r;
                bf16x8 av = *(const bf16x8*)&sH[i * 64 + ((cb ^ key8(i)) << 3)];
                zacc[a] = __builtin_amdgcn_mfma_f32_16x16x32_bf16(av, bv, zacc[a], 0, 0, 0);
            }
        }
        __syncthreads();   // sScale ready (rt0); prior pass z2 reads of sZ1 done
        // z1 epilogue -> sZ1 bf16 swizzled
        #pragma unroll
        for (int a = 0; a < 6; ++a) {
            #pragma unroll
            for (int reg = 0; reg < 4; ++reg) {
                int rl = a * 16 + q * 4 + reg;
                int m = wv * 16 + r;
                float v = leaky(fmaf(zacc[a][reg], sScale[r0 + rl], sDb[m]));
                int cb2 = m >> 3;
                int cbs2 = (cb2 & 8) | ((cb2 ^ key8(rl)) & 7);
                sZ1[rl * 128 + (cbs2 << 3) + (m & 7)] = f2bf(v);
            }
        }
        __syncthreads();   // sZ1 visible
        // z2 = leaky(z1 @ uw^T + ub) -> out; 24 tiles, 3 per wave
        {
            const int grp = wv >> 2, nt = wv & 3;
            f32x4 oacc[3];
            #pragma unroll
            for (int a = 0; a < 3; ++a) oacc[a] = (f32x4){0.f, 0.f, 0.f, 0.f};
            #pragma unroll
            for (int ks = 0; ks < 4; ++ks) {
                int cb = ks * 4 + q;
                int p = nt * 16 + r;
                bf16x8 bv = *(const bf16x8*)&uwB[p * 128 + cb * 8];
                #pragma unroll
                for (int a = 0; a < 3; ++a) {
                    int rl = (grp * 3 + a) * 16 + r;
                    int cbsA = (cb & 8) | ((cb ^ key8(rl)) & 7);
                    bf16x8 av = *(const bf16x8*)&sZ1[rl * 128 + (cbsA << 3)];
                    oacc[a] = __builtin_amdgcn_mfma_f32_16x16x32_bf16(av, bv, oacc[a], 0, 0, 0);
                }
            }
            #pragma unroll
            for (int a = 0; a < 3; ++a) {
                #pragma unroll
                for (int reg = 0; reg < 4; ++reg) {
                    int i = r0 + (grp * 3 + a) * 16 + q * 4 + reg;
                    int cp = nt * 16 + r;
                    out[(b * 384 + i) * 64 + cp] = leaky(oacc[a][reg] + sUb[cp]);
                }
            }
        }
        // no trailing barrier: next pass z1-MFMA touches only sH/global;
        // its post-MFMA barrier orders sZ1 overwrite after these z2 reads.
    }
}

extern "C" void kernel_launch(void* const* d_in, const int* in_sizes, int n_in,
                              void* d_out, int out_size, void* d_ws, size_t ws_size,
                              hipStream_t stream) {
    const float* x      = (const float*)d_in[0];
    const float* W      = (const float*)d_in[1];
    const float* bb     = (const float*)d_in[2];
    const float* pw     = (const float*)d_in[3];
    const float* pw1    = (const float*)d_in[4];
    const float* pb1    = (const float*)d_in[5];
    const float* pw2    = (const float*)d_in[6];
    const float* pb2    = (const float*)d_in[7];
    const float* proj_w = (const float*)d_in[8];
    const float* proj_b = (const float*)d_in[9];
    const float* down_w = (const float*)d_in[10];
    const float* down_b = (const float*)d_in[11];
    const float* up_w   = (const float*)d_in[12];
    const float* up_b   = (const float*)d_in[13];
    float* out = (float*)d_out;
    float* ws  = (float*)d_ws;

    prep<<<(34816 + 255) / 256, 256, 0, stream>>>(proj_w, down_w, up_w, ws);
    fused_main<<<1024, 512, 0, stream>>>(x, W, bb, pw, pw1, pb1, pw2, pb2,
                                         proj_b, down_b, up_b, ws, out);
}